// Round 11
// baseline (42.358 us; speedup 1.0000x reference)
//
#include <hip/hip_runtime.h>
#include <math.h>

#define CCH     128
#define HWTOK   4096
#define MROWS   512
#define THREADS 1024   // compute kernel: 16 waves; 256 blocks = 1 block/CU

#define FILLB   2048   // prep kernel: zero-fill blocks (256 thr, 8 f4 each)
#define FRAGB   32     // prep kernel: frag-table blocks
#define OUTF4   (32 * CCH * HWTOK / 4)   // 4,194,304 f4 = 64 MB

using short8  = __attribute__((ext_vector_type(8))) short;
using float16 = __attribute__((ext_vector_type(16))) float;
using f4      = __attribute__((ext_vector_type(4))) float;
using i4      = __attribute__((ext_vector_type(4))) int;

__device__ __forceinline__ unsigned f2bf_rne(float f) {
    unsigned u = __builtin_bit_cast(unsigned, f);
    return (u + 0x7FFFu + ((u >> 16) & 1u)) >> 16;
}
__device__ __forceinline__ float fmax3(float a, float b, float c) {
    return fmaxf(fmaxf(a, b), c);   // clang fuses to v_max3_f32
}

// ---------------------------------------------------------------------------
// Prep: (a) blocks [0, FILLB): zero-fill `out` with the exact pattern the
// runtime's fillBufferAligned uses (linear grid-stride f4) — measured on this
// chip at 6.7 TB/s with WRITE_SIZE = 1.00x buffer size, unlike every store
// pattern embedded in our mixed compute kernel (all ~1.9x amplified).
// (b) blocks [FILLB, FILLB+FRAGB): pre-normalized bf16 memory MFMA fragments:
// fid = (mt*8 + kstep)*64 + lane, lane = hi*32 + r5 holds
//   memory[mt*32 + r5][kstep*16 + hi*8 + j] * rinv(row), j = 0..7 (bf16)
// ---------------------------------------------------------------------------
__global__ __launch_bounds__(256) void prep_kernel(const float* __restrict__ mem,
                                                   i4* __restrict__ wsfrag,
                                                   float* __restrict__ out) {
    if (blockIdx.x < FILLB) {
        f4* o = reinterpret_cast<f4*>(out);
        int idx = blockIdx.x * 256 + threadIdx.x;
        f4 z = {0.f, 0.f, 0.f, 0.f};
        #pragma unroll
        for (int i = 0; i < 8; ++i)
            o[idx + i * (FILLB * 256)] = z;
        return;
    }

    int fid   = (blockIdx.x - FILLB) * 256 + threadIdx.x;   // 0..8191
    int mt    = fid >> 9;
    int rem   = fid & 511;
    int kstep = rem >> 6;
    int l     = rem & 63;
    int hi    = l >> 5, r5 = l & 31;
    int row   = mt * 32 + r5;
    int k0    = kstep * 16 + hi * 8;

    const float* mr = mem + (size_t)row * CCH;
    float s = 0.f;
    #pragma unroll
    for (int c = 0; c < CCH; c += 4) {
        f4 v = *reinterpret_cast<const f4*>(mr + c);
        s += v.x * v.x + v.y * v.y + v.z * v.z + v.w * v.w;
    }
    float sc = 1.0f / fmaxf(sqrtf(s), 1e-12f);

    unsigned p[4];
    #pragma unroll
    for (int j = 0; j < 4; ++j) {
        unsigned lo   = f2bf_rne(mr[k0 + 2 * j]     * sc);
        unsigned hi16 = f2bf_rne(mr[k0 + 2 * j + 1] * sc);
        p[j] = lo | (hi16 << 16);
    }
    i4 o; o.x = p[0]; o.y = p[1]; o.z = p[2]; o.w = p[3];
    wsfrag[fid] = o;
}

// ---------------------------------------------------------------------------
// Compute: 256 blocks x 16 waves. 128 KB fragment table staged in LDS once.
// Output zeros are PRE-WRITTEN by prep_kernel, so the common (no-hit) case
// issues ZERO stores — this kernel is a pure 67 MB x-read + MFMA max-reduce.
// Rare ballot-flagged waves recompute exact argmax (identical MFMAs, first-
// index tie-break) and overwrite only the hit tokens' 128 channels.
// ---------------------------------------------------------------------------
__global__ __launch_bounds__(THREADS, 4) void hardmem_mfma(
    const float* __restrict__ x, const float* __restrict__ mem,
    const i4* __restrict__ wsfrag, float* __restrict__ out)
{
    __shared__ i4 sfrag[8192];   // 128 KB — whole fragment table

    const int tid  = threadIdx.x;
    const int wid  = tid >> 6;                 // 0..15
    const int lane = tid & 63;
    const int l5   = lane & 31, hi = lane >> 5;

    const int b   = blockIdx.x >> 3;                     // 8 blocks/batch
    const int tb0 = (blockIdx.x & 7) * 512 + wid * 32;   // wave token base
    const float* xb = x + (size_t)b * CCH * HWTOK;

    // ---- stage fragment table -> LDS (L2-hot: 128 KB shared by all blocks)
    #pragma unroll
    for (int i = 0; i < 8; ++i) {
        int idx = tid + i * THREADS;           // 0..8191
        sfrag[idx] = wsfrag[idx];
    }

    // ---- build x B-fragment (token = tb0+l5); fp32 sum-of-squares on the fly
    // (r7 ordering: x-loads issued before the barrier, overlap sfrag staging)
    short8 bf[8];
    float  s2;
    {
        const float* xt = xb + tb0 + l5;
        float s = 0.f;
        #pragma unroll
        for (int kstep = 0; kstep < 8; ++kstep) {
            const int c0 = kstep * 16 + hi * 8;
            float v[8];
            #pragma unroll
            for (int j = 0; j < 8; ++j) v[j] = xt[(size_t)(c0 + j) * HWTOK];
            unsigned p[4];
            #pragma unroll
            for (int j = 0; j < 4; ++j) {
                s = fmaf(v[2 * j],     v[2 * j],     s);
                s = fmaf(v[2 * j + 1], v[2 * j + 1], s);
                unsigned u0 = __builtin_bit_cast(unsigned, v[2 * j]);
                unsigned u1 = __builtin_bit_cast(unsigned, v[2 * j + 1]);
                p[j] = (u0 >> 16) | (u1 & 0xFFFF0000u);   // truncate-to-bf16
            }
            i4 pk; pk.x = p[0]; pk.y = p[1]; pk.z = p[2]; pk.w = p[3];
            bf[kstep] = __builtin_bit_cast(short8, pk);
        }
        s2 = s;
    }

    __syncthreads();   // sfrag ready; everything below is wave-independent

    // ---- hot loop: max-only over 512 rows, A-frags from LDS
    float bmax = -1e30f;
    for (int mt = 0; mt < 16; ++mt) {
        short8 af[8];
        #pragma unroll
        for (int k = 0; k < 8; ++k)
            af[k] = __builtin_bit_cast(short8, sfrag[(mt * 8 + k) * 64 + lane]);

        float16 acc;
        #pragma unroll
        for (int r = 0; r < 16; ++r) acc[r] = 0.f;
        #pragma unroll
        for (int k = 0; k < 8; ++k)
            acc = __builtin_amdgcn_mfma_f32_32x32x16_bf16(af[k], bf[k], acc, 0, 0, 0);

        float m0 = fmax3(acc[0], acc[1], acc[2]);
        float m1 = fmax3(acc[3], acc[4], acc[5]);
        float m2 = fmax3(acc[6], acc[7], acc[8]);
        float m3 = fmax3(acc[9], acc[10], acc[11]);
        float m4 = fmax3(acc[12], acc[13], acc[14]);
        bmax = fmaxf(bmax, fmax3(fmax3(m0, m1, m2), fmax3(m3, m4, acc[15]), bmax));
    }

    // ---- threshold: bv/||x|| > 0.8  <=>  bv > 0.8*||x|| (norm > 0)
    bmax = fmaxf(bmax, __shfl_xor(bmax, 32));
    const float n2  = s2 + __shfl_xor(s2, 32);
    const bool  msk = bmax > 0.8f * fmaxf(sqrtf(n2), 1e-12f);

    const unsigned long long wb = __ballot(msk);
    if (wb == 0ULL) return;   // common case: zeros already written by prep

    // ---- rare path: exact argmax recompute (identical MFMAs), gather-store
    float bestv = -1e30f; int besti = 0;
    for (int mt = 0; mt < 16; ++mt) {
        short8 af[8];
        #pragma unroll
        for (int k = 0; k < 8; ++k)
            af[k] = __builtin_bit_cast(short8, sfrag[(mt * 8 + k) * 64 + lane]);
        float16 acc;
        #pragma unroll
        for (int r = 0; r < 16; ++r) acc[r] = 0.f;
        #pragma unroll
        for (int k = 0; k < 8; ++k)
            acc = __builtin_amdgcn_mfma_f32_32x32x16_bf16(af[k], bf[k], acc, 0, 0, 0);
        const int rbase = mt * 32 + 4 * hi;
        #pragma unroll
        for (int r = 0; r < 16; ++r) {
            // verified C/D map: row=(reg&3)+8*(reg>>2)+4*(lane>>5); ascending in r
            const int row = rbase + (r & 3) + 8 * (r >> 2);
            if (acc[r] > bestv) { bestv = acc[r]; besti = row; }
        }
    }
    float ov = __shfl_xor(bestv, 32);
    int   oi = __shfl_xor(besti, 32);
    if (ov > bestv || (ov == bestv && oi < besti)) { bestv = ov; besti = oi; }

    if (msk) {   // overwrite ONLY hit tokens (zeros elsewhere pre-filled)
        float* ob = out + (size_t)b * CCH * HWTOK;
        const int t = tb0 + l5;                // both hi-halves share token t
        const float* mrow = mem + (size_t)besti * CCH;
        #pragma unroll 8
        for (int k = 0; k < 64; ++k) {
            int c = hi + 2 * k;                // hi=0 even ch, hi=1 odd ch
            ob[(size_t)c * HWTOK + t] = mrow[c];
        }
    }
}

// ---------------------------------------------------------------------------
extern "C" void kernel_launch(void* const* d_in, const int* in_sizes, int n_in,
                              void* d_out, int out_size, void* d_ws, size_t ws_size,
                              hipStream_t stream) {
    const float* x   = (const float*)d_in[0];   // [32,128,64,64]
    const float* mem = (const float*)d_in[1];   // [512,128]
    float* out       = (float*)d_out;
    i4* wsfrag       = (i4*)d_ws;               // 128 KB fragment workspace

    prep_kernel<<<FILLB + FRAGB, 256, 0, stream>>>(mem, wsfrag, out);
    hardmem_mfma<<<256, THREADS, 0, stream>>>(x, mem, wsfrag, out);
}

// Round 12
// 42.139 us; speedup vs baseline: 1.0052x; 1.0052x over previous
//
#include <hip/hip_runtime.h>
#include <math.h>

#define CCH     128
#define HWTOK   4096
#define MROWS   512
#define THREADS 1024   // compute kernel: 16 waves; 256 blocks = 1 block/CU

#define FILLB   2048   // prep kernel: zero-fill blocks (256 thr, 8 f4 each)
#define FRAGB   32     // prep kernel: frag-table blocks
#define OUTF4   (32 * CCH * HWTOK / 4)   // 4,194,304 f4 = 64 MB

using short8  = __attribute__((ext_vector_type(8))) short;
using float16 = __attribute__((ext_vector_type(16))) float;
using f4      = __attribute__((ext_vector_type(4))) float;
using i4      = __attribute__((ext_vector_type(4))) int;

__device__ __forceinline__ unsigned f2bf_rne(float f) {
    unsigned u = __builtin_bit_cast(unsigned, f);
    return (u + 0x7FFFu + ((u >> 16) & 1u)) >> 16;
}
__device__ __forceinline__ float fmax3(float a, float b, float c) {
    return fmaxf(fmaxf(a, b), c);   // clang fuses to v_max3_f32
}

// ---------------------------------------------------------------------------
// Prep: (a) blocks [0, FILLB): zero-fill `out` with the exact pattern the
// runtime's fillBufferAligned uses (linear grid-stride f4) — measured on this
// chip at 6.7 TB/s with WRITE_SIZE = 1.00x buffer size, unlike every store
// pattern embedded in our mixed compute kernel (all ~1.9x amplified).
// (b) blocks [FILLB, FILLB+FRAGB): pre-normalized bf16 memory MFMA fragments:
// fid = (mt*8 + kstep)*64 + lane, lane = hi*32 + r5 holds
//   memory[mt*32 + r5][kstep*16 + hi*8 + j] * rinv(row), j = 0..7 (bf16)
// ---------------------------------------------------------------------------
__global__ __launch_bounds__(256) void prep_kernel(const float* __restrict__ mem,
                                                   i4* __restrict__ wsfrag,
                                                   float* __restrict__ out) {
    if (blockIdx.x < FILLB) {
        f4* o = reinterpret_cast<f4*>(out);
        int idx = blockIdx.x * 256 + threadIdx.x;
        f4 z = {0.f, 0.f, 0.f, 0.f};
        #pragma unroll
        for (int i = 0; i < 8; ++i)
            o[idx + i * (FILLB * 256)] = z;
        return;
    }

    int fid   = (blockIdx.x - FILLB) * 256 + threadIdx.x;   // 0..8191
    int mt    = fid >> 9;
    int rem   = fid & 511;
    int kstep = rem >> 6;
    int l     = rem & 63;
    int hi    = l >> 5, r5 = l & 31;
    int row   = mt * 32 + r5;
    int k0    = kstep * 16 + hi * 8;

    const float* mr = mem + (size_t)row * CCH;
    float s = 0.f;
    #pragma unroll
    for (int c = 0; c < CCH; c += 4) {
        f4 v = *reinterpret_cast<const f4*>(mr + c);
        s += v.x * v.x + v.y * v.y + v.z * v.z + v.w * v.w;
    }
    float sc = 1.0f / fmaxf(sqrtf(s), 1e-12f);

    unsigned p[4];
    #pragma unroll
    for (int j = 0; j < 4; ++j) {
        unsigned lo   = f2bf_rne(mr[k0 + 2 * j]     * sc);
        unsigned hi16 = f2bf_rne(mr[k0 + 2 * j + 1] * sc);
        p[j] = lo | (hi16 << 16);
    }
    i4 o; o.x = p[0]; o.y = p[1]; o.z = p[2]; o.w = p[3];
    wsfrag[fid] = o;
}

// ---------------------------------------------------------------------------
// Compute: 256 blocks x 16 waves. 128 KB fragment table staged in LDS once.
// Output zeros are PRE-WRITTEN by prep_kernel, so the common (no-hit) case
// issues ZERO stores — this kernel is a pure 67 MB x-read + MFMA max-reduce.
// Rare ballot-flagged waves recompute exact argmax (identical MFMAs, first-
// index tie-break) and overwrite only the hit tokens' 128 channels.
// ---------------------------------------------------------------------------
__global__ __launch_bounds__(THREADS, 4) void hardmem_mfma(
    const float* __restrict__ x, const float* __restrict__ mem,
    const i4* __restrict__ wsfrag, float* __restrict__ out)
{
    __shared__ i4 sfrag[8192];   // 128 KB — whole fragment table

    const int tid  = threadIdx.x;
    const int wid  = tid >> 6;                 // 0..15
    const int lane = tid & 63;
    const int l5   = lane & 31, hi = lane >> 5;

    const int b   = blockIdx.x >> 3;                     // 8 blocks/batch
    const int tb0 = (blockIdx.x & 7) * 512 + wid * 32;   // wave token base
    const float* xb = x + (size_t)b * CCH * HWTOK;

    // ---- stage fragment table -> LDS (L2-hot: 128 KB shared by all blocks)
    #pragma unroll
    for (int i = 0; i < 8; ++i) {
        int idx = tid + i * THREADS;           // 0..8191
        sfrag[idx] = wsfrag[idx];
    }

    // ---- build x B-fragment (token = tb0+l5); fp32 sum-of-squares on the fly
    // (r7 ordering: x-loads issued before the barrier, overlap sfrag staging)
    short8 bf[8];
    float  s2;
    {
        const float* xt = xb + tb0 + l5;
        float s = 0.f;
        #pragma unroll
        for (int kstep = 0; kstep < 8; ++kstep) {
            const int c0 = kstep * 16 + hi * 8;
            float v[8];
            #pragma unroll
            for (int j = 0; j < 8; ++j) v[j] = xt[(size_t)(c0 + j) * HWTOK];
            unsigned p[4];
            #pragma unroll
            for (int j = 0; j < 4; ++j) {
                s = fmaf(v[2 * j],     v[2 * j],     s);
                s = fmaf(v[2 * j + 1], v[2 * j + 1], s);
                unsigned u0 = __builtin_bit_cast(unsigned, v[2 * j]);
                unsigned u1 = __builtin_bit_cast(unsigned, v[2 * j + 1]);
                p[j] = (u0 >> 16) | (u1 & 0xFFFF0000u);   // truncate-to-bf16
            }
            i4 pk; pk.x = p[0]; pk.y = p[1]; pk.z = p[2]; pk.w = p[3];
            bf[kstep] = __builtin_bit_cast(short8, pk);
        }
        s2 = s;
    }

    __syncthreads();   // sfrag ready; everything below is wave-independent

    // ---- hot loop: max-only over 512 rows, A-frags from LDS
    float bmax = -1e30f;
    for (int mt = 0; mt < 16; ++mt) {
        short8 af[8];
        #pragma unroll
        for (int k = 0; k < 8; ++k)
            af[k] = __builtin_bit_cast(short8, sfrag[(mt * 8 + k) * 64 + lane]);

        float16 acc;
        #pragma unroll
        for (int r = 0; r < 16; ++r) acc[r] = 0.f;
        #pragma unroll
        for (int k = 0; k < 8; ++k)
            acc = __builtin_amdgcn_mfma_f32_32x32x16_bf16(af[k], bf[k], acc, 0, 0, 0);

        float m0 = fmax3(acc[0], acc[1], acc[2]);
        float m1 = fmax3(acc[3], acc[4], acc[5]);
        float m2 = fmax3(acc[6], acc[7], acc[8]);
        float m3 = fmax3(acc[9], acc[10], acc[11]);
        float m4 = fmax3(acc[12], acc[13], acc[14]);
        bmax = fmaxf(bmax, fmax3(fmax3(m0, m1, m2), fmax3(m3, m4, acc[15]), bmax));
    }

    // ---- threshold: bv/||x|| > 0.8  <=>  bv > 0.8*||x|| (norm > 0)
    bmax = fmaxf(bmax, __shfl_xor(bmax, 32));
    const float n2  = s2 + __shfl_xor(s2, 32);
    const bool  msk = bmax > 0.8f * fmaxf(sqrtf(n2), 1e-12f);

    const unsigned long long wb = __ballot(msk);
    if (wb == 0ULL) return;   // common case: zeros already written by prep

    // ---- rare path: exact argmax recompute (identical MFMAs), gather-store
    float bestv = -1e30f; int besti = 0;
    for (int mt = 0; mt < 16; ++mt) {
        short8 af[8];
        #pragma unroll
        for (int k = 0; k < 8; ++k)
            af[k] = __builtin_bit_cast(short8, sfrag[(mt * 8 + k) * 64 + lane]);
        float16 acc;
        #pragma unroll
        for (int r = 0; r < 16; ++r) acc[r] = 0.f;
        #pragma unroll
        for (int k = 0; k < 8; ++k)
            acc = __builtin_amdgcn_mfma_f32_32x32x16_bf16(af[k], bf[k], acc, 0, 0, 0);
        const int rbase = mt * 32 + 4 * hi;
        #pragma unroll
        for (int r = 0; r < 16; ++r) {
            // verified C/D map: row=(reg&3)+8*(reg>>2)+4*(lane>>5); ascending in r
            const int row = rbase + (r & 3) + 8 * (r >> 2);
            if (acc[r] > bestv) { bestv = acc[r]; besti = row; }
        }
    }
    float ov = __shfl_xor(bestv, 32);
    int   oi = __shfl_xor(besti, 32);
    if (ov > bestv || (ov == bestv && oi < besti)) { bestv = ov; besti = oi; }

    if (msk) {   // overwrite ONLY hit tokens (zeros elsewhere pre-filled)
        float* ob = out + (size_t)b * CCH * HWTOK;
        const int t = tb0 + l5;                // both hi-halves share token t
        const float* mrow = mem + (size_t)besti * CCH;
        #pragma unroll 8
        for (int k = 0; k < 64; ++k) {
            int c = hi + 2 * k;                // hi=0 even ch, hi=1 odd ch
            ob[(size_t)c * HWTOK + t] = mrow[c];
        }
    }
}

// ---------------------------------------------------------------------------
extern "C" void kernel_launch(void* const* d_in, const int* in_sizes, int n_in,
                              void* d_out, int out_size, void* d_ws, size_t ws_size,
                              hipStream_t stream) {
    const float* x   = (const float*)d_in[0];   // [32,128,64,64]
    const float* mem = (const float*)d_in[1];   // [512,128]
    float* out       = (float*)d_out;
    i4* wsfrag       = (i4*)d_ws;               // 128 KB fragment workspace

    prep_kernel<<<FILLB + FRAGB, 256, 0, stream>>>(mem, wsfrag, out);
    hardmem_mfma<<<256, THREADS, 0, stream>>>(x, mem, wsfrag, out);
}

// Round 13
// 42.136 us; speedup vs baseline: 1.0053x; 1.0001x over previous
//
#include <hip/hip_runtime.h>
#include <math.h>

#define CCH     128
#define HWTOK   4096
#define MROWS   512
#define THREADS 512    // compute kernel: 8 waves; 256 blocks = 1 block/CU

#define FILLB   2048   // prep kernel: zero-fill blocks (256 thr, 8 f4 each)
#define FRAGB   32     // prep kernel: frag-table blocks

using short8  = __attribute__((ext_vector_type(8))) short;
using float16 = __attribute__((ext_vector_type(16))) float;
using f4      = __attribute__((ext_vector_type(4))) float;
using i4      = __attribute__((ext_vector_type(4))) int;

__device__ __forceinline__ unsigned f2bf_rne(float f) {
    unsigned u = __builtin_bit_cast(unsigned, f);
    return (u + 0x7FFFu + ((u >> 16) & 1u)) >> 16;
}
__device__ __forceinline__ float fmax3(float a, float b, float c) {
    return fmaxf(fmaxf(a, b), c);   // clang fuses to v_max3_f32
}

// ---------------------------------------------------------------------------
// Prep: (a) blocks [0, FILLB): zero-fill `out` (linear grid-stride f4 — the
// fillBufferAligned pattern, measured 6.7 TB/s, WRITE_SIZE = 1.00x).
// (b) blocks [FILLB, FILLB+FRAGB): pre-normalized bf16 memory MFMA fragments:
// fid = (mt*8 + kstep)*64 + lane, lane = hi*32 + r5 holds
//   memory[mt*32 + r5][kstep*16 + hi*8 + j] * rinv(row), j = 0..7 (bf16)
// ---------------------------------------------------------------------------
__global__ __launch_bounds__(256) void prep_kernel(const float* __restrict__ mem,
                                                   i4* __restrict__ wsfrag,
                                                   float* __restrict__ out) {
    if (blockIdx.x < FILLB) {
        f4* o = reinterpret_cast<f4*>(out);
        int idx = blockIdx.x * 256 + threadIdx.x;
        f4 z = {0.f, 0.f, 0.f, 0.f};
        #pragma unroll
        for (int i = 0; i < 8; ++i)
            o[idx + i * (FILLB * 256)] = z;
        return;
    }

    int fid   = (blockIdx.x - FILLB) * 256 + threadIdx.x;   // 0..8191
    int mt    = fid >> 9;
    int rem   = fid & 511;
    int kstep = rem >> 6;
    int l     = rem & 63;
    int hi    = l >> 5, r5 = l & 31;
    int row   = mt * 32 + r5;
    int k0    = kstep * 16 + hi * 8;

    const float* mr = mem + (size_t)row * CCH;
    float s = 0.f;
    #pragma unroll
    for (int c = 0; c < CCH; c += 4) {
        f4 v = *reinterpret_cast<const f4*>(mr + c);
        s += v.x * v.x + v.y * v.y + v.z * v.z + v.w * v.w;
    }
    float sc = 1.0f / fmaxf(sqrtf(s), 1e-12f);

    unsigned p[4];
    #pragma unroll
    for (int j = 0; j < 4; ++j) {
        unsigned lo   = f2bf_rne(mr[k0 + 2 * j]     * sc);
        unsigned hi16 = f2bf_rne(mr[k0 + 2 * j + 1] * sc);
        p[j] = lo | (hi16 << 16);
    }
    i4 o; o.x = p[0]; o.y = p[1]; o.z = p[2]; o.w = p[3];
    wsfrag[fid] = o;
}

// ---------------------------------------------------------------------------
// Compute: 256 blocks x 8 waves (512 thr). 128 KB fragment table in LDS.
// KEY CHANGE vs r7/r12: wave owns 64 tokens (bf[2][8]); hot loop is mt-OUTER
// so each A-fragment LDS read feeds 16 MFMAs (2 token-tiles) instead of 8 —
// halves per-token LDS traffic (r7: 16 waves x 128KB = 2MB/CU ~ 10us of
// ds_read_b128 serialization, the hidden dominant cost). Two independent
// acc chains per mt hide MFMA latency. Zeros pre-written by prep; common
// (no-hit) case stores nothing.
// ---------------------------------------------------------------------------
__global__ __launch_bounds__(THREADS, 2) void hardmem_mfma(
    const float* __restrict__ x, const float* __restrict__ mem,
    const i4* __restrict__ wsfrag, float* __restrict__ out)
{
    __shared__ i4 sfrag[8192];   // 128 KB — whole fragment table

    const int tid  = threadIdx.x;
    const int wid  = tid >> 6;                 // 0..7
    const int lane = tid & 63;
    const int l5   = lane & 31, hi = lane >> 5;

    const int b   = blockIdx.x >> 3;                     // 8 blocks/batch
    const int tb0 = (blockIdx.x & 7) * 512 + wid * 64;   // wave token base (64 tokens)
    const float* xb = x + (size_t)b * CCH * HWTOK;

    // ---- stage fragment table -> LDS (L2-hot: 128 KB shared by all blocks)
    #pragma unroll
    for (int i = 0; i < 16; ++i) {
        int idx = tid + i * THREADS;           // 0..8191
        sfrag[idx] = wsfrag[idx];
    }

    // ---- build x B-fragments for 2 token tiles; fp32 sum-of-squares on the fly
    short8 bf0[8], bf1[8];
    float  s2[2];
    #pragma unroll
    for (int tt = 0; tt < 2; ++tt) {
        const float* xt = xb + tb0 + tt * 32 + l5;
        float s = 0.f;
        #pragma unroll
        for (int kstep = 0; kstep < 8; ++kstep) {
            const int c0 = kstep * 16 + hi * 8;
            float v[8];
            #pragma unroll
            for (int j = 0; j < 8; ++j) v[j] = xt[(size_t)(c0 + j) * HWTOK];
            unsigned p[4];
            #pragma unroll
            for (int j = 0; j < 4; ++j) {
                s = fmaf(v[2 * j],     v[2 * j],     s);
                s = fmaf(v[2 * j + 1], v[2 * j + 1], s);
                unsigned u0 = __builtin_bit_cast(unsigned, v[2 * j]);
                unsigned u1 = __builtin_bit_cast(unsigned, v[2 * j + 1]);
                p[j] = (u0 >> 16) | (u1 & 0xFFFF0000u);   // truncate-to-bf16
            }
            i4 pk; pk.x = p[0]; pk.y = p[1]; pk.z = p[2]; pk.w = p[3];
            if (tt == 0) bf0[kstep] = __builtin_bit_cast(short8, pk);
            else         bf1[kstep] = __builtin_bit_cast(short8, pk);
        }
        s2[tt] = s;
    }

    __syncthreads();   // sfrag ready; everything below is wave-independent

    // ---- hot loop: mt-outer, af reused across both token tiles
    float bmax0 = -1e30f, bmax1 = -1e30f;
    for (int mt = 0; mt < 16; ++mt) {
        short8 af[8];
        #pragma unroll
        for (int k = 0; k < 8; ++k)
            af[k] = __builtin_bit_cast(short8, sfrag[(mt * 8 + k) * 64 + lane]);

        float16 acc0, acc1;
        #pragma unroll
        for (int r = 0; r < 16; ++r) { acc0[r] = 0.f; acc1[r] = 0.f; }
        #pragma unroll
        for (int k = 0; k < 8; ++k) {   // two independent chains hide latency
            acc0 = __builtin_amdgcn_mfma_f32_32x32x16_bf16(af[k], bf0[k], acc0, 0, 0, 0);
            acc1 = __builtin_amdgcn_mfma_f32_32x32x16_bf16(af[k], bf1[k], acc1, 0, 0, 0);
        }
        {
            float m0 = fmax3(acc0[0], acc0[1], acc0[2]);
            float m1 = fmax3(acc0[3], acc0[4], acc0[5]);
            float m2 = fmax3(acc0[6], acc0[7], acc0[8]);
            float m3 = fmax3(acc0[9], acc0[10], acc0[11]);
            float m4 = fmax3(acc0[12], acc0[13], acc0[14]);
            bmax0 = fmaxf(bmax0, fmax3(fmax3(m0, m1, m2), fmax3(m3, m4, acc0[15]), bmax0));
        }
        {
            float m0 = fmax3(acc1[0], acc1[1], acc1[2]);
            float m1 = fmax3(acc1[3], acc1[4], acc1[5]);
            float m2 = fmax3(acc1[6], acc1[7], acc1[8]);
            float m3 = fmax3(acc1[9], acc1[10], acc1[11]);
            float m4 = fmax3(acc1[12], acc1[13], acc1[14]);
            bmax1 = fmaxf(bmax1, fmax3(fmax3(m0, m1, m2), fmax3(m3, m4, acc1[15]), bmax1));
        }
    }

    // ---- threshold: bv/||x|| > 0.8  <=>  bv > 0.8*||x|| (norm > 0)
    bmax0 = fmaxf(bmax0, __shfl_xor(bmax0, 32));
    bmax1 = fmaxf(bmax1, __shfl_xor(bmax1, 32));
    const float n20 = s2[0] + __shfl_xor(s2[0], 32);
    const float n21 = s2[1] + __shfl_xor(s2[1], 32);
    const bool msk0 = bmax0 > 0.8f * fmaxf(sqrtf(n20), 1e-12f);
    const bool msk1 = bmax1 > 0.8f * fmaxf(sqrtf(n21), 1e-12f);

    const unsigned long long wb = __ballot(msk0) | __ballot(msk1);
    if (wb == 0ULL) return;   // common case: zeros already written by prep

    // ---- rare path: exact argmax recompute (identical MFMAs), gather-store
    float bestv0 = -1e30f, bestv1 = -1e30f;
    int   besti0 = 0,      besti1 = 0;
    for (int mt = 0; mt < 16; ++mt) {
        short8 af[8];
        #pragma unroll
        for (int k = 0; k < 8; ++k)
            af[k] = __builtin_bit_cast(short8, sfrag[(mt * 8 + k) * 64 + lane]);
        float16 acc0, acc1;
        #pragma unroll
        for (int r = 0; r < 16; ++r) { acc0[r] = 0.f; acc1[r] = 0.f; }
        #pragma unroll
        for (int k = 0; k < 8; ++k) {
            acc0 = __builtin_amdgcn_mfma_f32_32x32x16_bf16(af[k], bf0[k], acc0, 0, 0, 0);
            acc1 = __builtin_amdgcn_mfma_f32_32x32x16_bf16(af[k], bf1[k], acc1, 0, 0, 0);
        }
        const int rbase = mt * 32 + 4 * hi;
        #pragma unroll
        for (int r = 0; r < 16; ++r) {
            // verified C/D map: row=(reg&3)+8*(reg>>2)+4*(lane>>5); ascending in r
            const int row = rbase + (r & 3) + 8 * (r >> 2);
            if (acc0[r] > bestv0) { bestv0 = acc0[r]; besti0 = row; }
            if (acc1[r] > bestv1) { bestv1 = acc1[r]; besti1 = row; }
        }
    }
    {
        float ov = __shfl_xor(bestv0, 32); int oi = __shfl_xor(besti0, 32);
        if (ov > bestv0 || (ov == bestv0 && oi < besti0)) { bestv0 = ov; besti0 = oi; }
        ov = __shfl_xor(bestv1, 32); oi = __shfl_xor(besti1, 32);
        if (ov > bestv1 || (ov == bestv1 && oi < besti1)) { bestv1 = ov; besti1 = oi; }
    }

    float* ob = out + (size_t)b * CCH * HWTOK;
    if (msk0) {   // overwrite ONLY hit tokens (zeros elsewhere pre-filled)
        const int t = tb0 + l5;
        const float* mrow = mem + (size_t)besti0 * CCH;
        #pragma unroll 8
        for (int k = 0; k < 64; ++k) {
            int c = hi + 2 * k;
            ob[(size_t)c * HWTOK + t] = mrow[c];
        }
    }
    if (msk1) {
        const int t = tb0 + 32 + l5;
        const float* mrow = mem + (size_t)besti1 * CCH;
        #pragma unroll 8
        for (int k = 0; k < 64; ++k) {
            int c = hi + 2 * k;
            ob[(size_t)c * HWTOK + t] = mrow[c];
        }
    }
}

// ---------------------------------------------------------------------------
extern "C" void kernel_launch(void* const* d_in, const int* in_sizes, int n_in,
                              void* d_out, int out_size, void* d_ws, size_t ws_size,
                              hipStream_t stream) {
    const float* x   = (const float*)d_in[0];   // [32,128,64,64]
    const float* mem = (const float*)d_in[1];   // [512,128]
    float* out       = (float*)d_out;
    i4* wsfrag       = (i4*)d_ws;               // 128 KB fragment workspace

    prep_kernel<<<FILLB + FRAGB, 256, 0, stream>>>(mem, wsfrag, out);
    hardmem_mfma<<<256, THREADS, 0, stream>>>(x, mem, wsfrag, out);
}

// Round 14
// 40.360 us; speedup vs baseline: 1.0495x; 1.0440x over previous
//
#include <hip/hip_runtime.h>
#include <math.h>

#define CCH     128
#define HWTOK   4096
#define MROWS   512
#define THREADS 1024   // 16 waves; 256 blocks = 1 block/CU

using short8  = __attribute__((ext_vector_type(8))) short;
using float16 = __attribute__((ext_vector_type(16))) float;
using f4      = __attribute__((ext_vector_type(4))) float;
using i4      = __attribute__((ext_vector_type(4))) int;

__device__ __forceinline__ unsigned f2bf_rne(float f) {
    unsigned u = __builtin_bit_cast(unsigned, f);
    return (u + 0x7FFFu + ((u >> 16) & 1u)) >> 16;
}
__device__ __forceinline__ float fmax3(float a, float b, float c) {
    return fmaxf(fmaxf(a, b), c);   // clang fuses to v_max3_f32
}

// ---------------------------------------------------------------------------
// Prep: pre-normalized bf16 memory rows as MFMA A-fragments in ws (frag table
// only — the output zero-fill moved into the main kernel).
// fid = (mt*8 + kstep)*64 + lane, lane = hi*32 + r5 holds
//   memory[mt*32 + r5][kstep*16 + hi*8 + j] * rinv(row), j = 0..7 (bf16)
// ---------------------------------------------------------------------------
__global__ __launch_bounds__(256) void frag_kernel(const float* __restrict__ mem,
                                                   i4* __restrict__ wsfrag) {
    int fid   = blockIdx.x * 256 + threadIdx.x;   // 0..8191
    int mt    = fid >> 9;
    int rem   = fid & 511;
    int kstep = rem >> 6;
    int l     = rem & 63;
    int hi    = l >> 5, r5 = l & 31;
    int row   = mt * 32 + r5;
    int k0    = kstep * 16 + hi * 8;

    const float* mr = mem + (size_t)row * CCH;
    float s = 0.f;
    #pragma unroll
    for (int c = 0; c < CCH; c += 4) {
        f4 v = *reinterpret_cast<const f4*>(mr + c);
        s += v.x * v.x + v.y * v.y + v.z * v.z + v.w * v.w;
    }
    float sc = 1.0f / fmaxf(sqrtf(s), 1e-12f);

    unsigned p[4];
    #pragma unroll
    for (int j = 0; j < 4; ++j) {
        unsigned lo   = f2bf_rne(mr[k0 + 2 * j]     * sc);
        unsigned hi16 = f2bf_rne(mr[k0 + 2 * j + 1] * sc);
        p[j] = lo | (hi16 << 16);
    }
    i4 o; o.x = p[0]; o.y = p[1]; o.z = p[2]; o.w = p[3];
    wsfrag[fid] = o;
}

// ---------------------------------------------------------------------------
// Main: 256 blocks x 16 waves (r7 geometry, best measured). NEW vs r7:
// 1. Block zero-fills its OWN 256 KB output region FIRST (f4, 1 KB contiguous
//    per wave instruction — the fillBufferAligned shape, measured clean at
//    6.7 TB/s). Stores are fire-and-forget; they drain under the sfrag
//    staging + x-build + barrier.
// 2. Common (no-hit) case then stores NOTHING after the hot loop.
// 3. Rare hit path overwrites only hit tokens — ordered after the fill by
//    the barrier's vmcnt drain; fills and hits are block-owned (no races).
// ---------------------------------------------------------------------------
__global__ __launch_bounds__(THREADS, 4) void hardmem_mfma(
    const float* __restrict__ x, const float* __restrict__ mem,
    const i4* __restrict__ wsfrag, float* __restrict__ out)
{
    __shared__ i4 sfrag[8192];   // 128 KB — whole fragment table

    const int tid  = threadIdx.x;
    const int wid  = tid >> 6;                 // 0..15
    const int lane = tid & 63;
    const int l5   = lane & 31, hi = lane >> 5;

    const int b    = blockIdx.x >> 3;                    // 8 blocks/batch
    const int treg = (blockIdx.x & 7) * 512;             // block token region
    const int tb0  = treg + wid * 32;                    // wave token base
    const float* xb = x + (size_t)b * CCH * HWTOK;
    float* obase    = out + (size_t)b * CCH * HWTOK;

    // ---- 1. zero-fill own output region: 128 ch x 512 tokens = 16384 f4.
    // Per instruction: block covers 8 channels x 512B; each wave writes 1 KB
    // contiguous (64 lanes x 16B) — locally identical to fillBufferAligned.
    {
        float* oreg = obase + treg;
        f4 z = {0.f, 0.f, 0.f, 0.f};
        #pragma unroll
        for (int i = 0; i < 16; ++i) {
            int idx = tid + i * THREADS;       // 0..16383
            int c = idx >> 7, o4 = idx & 127;  // channel, f4-offset in channel
            *reinterpret_cast<f4*>(oreg + (size_t)c * HWTOK + o4 * 4) = z;
        }
    }

    // ---- 2. stage fragment table -> LDS (L2-hot, 128 KB)
    #pragma unroll
    for (int i = 0; i < 8; ++i) {
        int idx = tid + i * THREADS;           // 0..8191
        sfrag[idx] = wsfrag[idx];
    }

    // ---- 3. build x B-fragment (token = tb0+l5); fp32 sum-of-squares
    short8 bf[8];
    float  s2;
    {
        const float* xt = xb + tb0 + l5;
        float s = 0.f;
        #pragma unroll
        for (int kstep = 0; kstep < 8; ++kstep) {
            const int c0 = kstep * 16 + hi * 8;
            float v[8];
            #pragma unroll
            for (int j = 0; j < 8; ++j) v[j] = xt[(size_t)(c0 + j) * HWTOK];
            unsigned p[4];
            #pragma unroll
            for (int j = 0; j < 4; ++j) {
                s = fmaf(v[2 * j],     v[2 * j],     s);
                s = fmaf(v[2 * j + 1], v[2 * j + 1], s);
                unsigned u0 = __builtin_bit_cast(unsigned, v[2 * j]);
                unsigned u1 = __builtin_bit_cast(unsigned, v[2 * j + 1]);
                p[j] = (u0 >> 16) | (u1 & 0xFFFF0000u);   // truncate-to-bf16
            }
            i4 pk; pk.x = p[0]; pk.y = p[1]; pk.z = p[2]; pk.w = p[3];
            bf[kstep] = __builtin_bit_cast(short8, pk);
        }
        s2 = s;
    }

    __syncthreads();   // sfrag visible + fill stores drained (vmcnt(0));
                       // everything below is wave-independent

    // ---- 4. hot loop: max-only over 512 rows, A-frags from LDS
    float bmax = -1e30f;
    for (int mt = 0; mt < 16; ++mt) {
        short8 af[8];
        #pragma unroll
        for (int k = 0; k < 8; ++k)
            af[k] = __builtin_bit_cast(short8, sfrag[(mt * 8 + k) * 64 + lane]);

        float16 acc;
        #pragma unroll
        for (int r = 0; r < 16; ++r) acc[r] = 0.f;
        #pragma unroll
        for (int k = 0; k < 8; ++k)
            acc = __builtin_amdgcn_mfma_f32_32x32x16_bf16(af[k], bf[k], acc, 0, 0, 0);

        float m0 = fmax3(acc[0], acc[1], acc[2]);
        float m1 = fmax3(acc[3], acc[4], acc[5]);
        float m2 = fmax3(acc[6], acc[7], acc[8]);
        float m3 = fmax3(acc[9], acc[10], acc[11]);
        float m4 = fmax3(acc[12], acc[13], acc[14]);
        bmax = fmaxf(bmax, fmax3(fmax3(m0, m1, m2), fmax3(m3, m4, acc[15]), bmax));
    }

    // ---- threshold: bv/||x|| > 0.8  <=>  bv > 0.8*||x|| (norm > 0)
    bmax = fmaxf(bmax, __shfl_xor(bmax, 32));
    const float n2  = s2 + __shfl_xor(s2, 32);
    const bool  msk = bmax > 0.8f * fmaxf(sqrtf(n2), 1e-12f);

    const unsigned long long wb = __ballot(msk);
    if (wb == 0ULL) return;   // common case: zeros already in place

    // ---- rare path: exact argmax recompute (identical MFMAs), overwrite hits
    float bestv = -1e30f; int besti = 0;
    for (int mt = 0; mt < 16; ++mt) {
        short8 af[8];
        #pragma unroll
        for (int k = 0; k < 8; ++k)
            af[k] = __builtin_bit_cast(short8, sfrag[(mt * 8 + k) * 64 + lane]);
        float16 acc;
        #pragma unroll
        for (int r = 0; r < 16; ++r) acc[r] = 0.f;
        #pragma unroll
        for (int k = 0; k < 8; ++k)
            acc = __builtin_amdgcn_mfma_f32_32x32x16_bf16(af[k], bf[k], acc, 0, 0, 0);
        const int rbase = mt * 32 + 4 * hi;
        #pragma unroll
        for (int r = 0; r < 16; ++r) {
            // verified C/D map: row=(reg&3)+8*(reg>>2)+4*(lane>>5); ascending in r
            const int row = rbase + (r & 3) + 8 * (r >> 2);
            if (acc[r] > bestv) { bestv = acc[r]; besti = row; }
        }
    }
    float ov = __shfl_xor(bestv, 32);
    int   oi = __shfl_xor(besti, 32);
    if (ov > bestv || (ov == bestv && oi < besti)) { bestv = ov; besti = oi; }

    if (msk) {   // overwrite ONLY hit tokens (zeros elsewhere pre-filled)
        const int t = tb0 + l5;                // both hi-halves share token t
        const float* mrow = mem + (size_t)besti * CCH;
        #pragma unroll 8
        for (int k = 0; k < 64; ++k) {
            int c = hi + 2 * k;                // hi=0 even ch, hi=1 odd ch
            obase[(size_t)c * HWTOK + t] = mrow[c];
        }
    }
}

// ---------------------------------------------------------------------------
extern "C" void kernel_launch(void* const* d_in, const int* in_sizes, int n_in,
                              void* d_out, int out_size, void* d_ws, size_t ws_size,
                              hipStream_t stream) {
    const float* x   = (const float*)d_in[0];   // [32,128,64,64]
    const float* mem = (const float*)d_in[1];   // [512,128]
    float* out       = (float*)d_out;
    i4* wsfrag       = (i4*)d_ws;               // 128 KB fragment workspace

    frag_kernel<<<32, 256, 0, stream>>>(mem, wsfrag);
    hardmem_mfma<<<256, THREADS, 0, stream>>>(x, mem, wsfrag, out);
}